// Round 5
// baseline (2760.400 us; speedup 1.0000x reference)
//
#include <hip/hip_runtime.h>
#include <hip/hip_bf16.h>

#define N_NODES 50000
#define N_EDGES 800000
#define DIN_    64
#define EIN_    16
#define H_      300
#define R_OUT   1024
#define G_GR    256
#define DEPTH_  5
#define KPAD    320
#define NPAD    50048   // multiple of 64 >= N_NODES

typedef unsigned short ushort_t;
typedef __attribute__((ext_vector_type(8))) short bf16x8;
typedef __attribute__((ext_vector_type(4))) float f32x4;

__device__ __forceinline__ ushort_t f2b(float f) {
  unsigned x = __float_as_uint(f);
  unsigned r = (x + 0x7fffu + ((x >> 16) & 1u)) >> 16;  // RTN-even
  return (ushort_t)r;
}
__device__ __forceinline__ float b2f(ushort_t u) {
  return __uint_as_float((unsigned)u << 16);
}

// ---------------- weight packing (once per call) ----------------
// Pack W1/W2 (fp32 [DEPTH][300][300], k-major) into bf16 frag layout
// Bp[i][kg][n][j] , k = kg*8+j, zero-padded to 320x320.
__global__ void pack_weights(const float* __restrict__ W1, const float* __restrict__ W2,
                             ushort_t* __restrict__ Bp1, ushort_t* __restrict__ Bp2) {
  int idx = blockIdx.x * 256 + threadIdx.x;
  const int per = DEPTH_ * 40 * KPAD * 8;  // 512000
  if (idx >= 2 * per) return;
  const float* W = W1;
  ushort_t* Bp = Bp1;
  int t = idx;
  if (t >= per) { t -= per; W = W2; Bp = Bp2; }
  int j  = t & 7;
  int n  = (t >> 3) % KPAD;
  int kg = ((t >> 3) / KPAD) % 40;
  int i  = t / (40 * KPAD * 8);
  int k  = kg * 8 + j;
  float v = (k < H_ && n < H_) ? W[(i * H_ + k) * H_ + n] : 0.f;
  Bp[t] = f2b(v);
}

// ---------------- CSR build (once per call) ----------------
__global__ void hist_deg(const int* __restrict__ dst, int* __restrict__ deg) {
  int e = blockIdx.x * 256 + threadIdx.x;
  if (e < N_EDGES) atomicAdd(deg + dst[e], 1);
}

// single-block exclusive scan of deg[0..N_NODES) -> off, off[N_NODES]=total
__global__ __launch_bounds__(1024) void exscan_kernel(const int* __restrict__ deg,
                                                      int* __restrict__ off) {
  __shared__ int wsum[16];
  __shared__ int carry_s;
  int lane = threadIdx.x & 63;
  int wv = threadIdx.x >> 6;
  if (threadIdx.x == 0) carry_s = 0;
  __syncthreads();
  for (int base = 0; base < N_NODES; base += 1024) {
    int i = base + (int)threadIdx.x;
    int orig = (i < N_NODES) ? deg[i] : 0;
    int v = orig;
#pragma unroll
    for (int s = 1; s < 64; s <<= 1) {
      int u = __shfl_up(v, s);
      if (lane >= s) v += u;
    }
    if (lane == 63) wsum[wv] = v;
    __syncthreads();
    if (wv == 0) {
      int t = (lane < 16) ? wsum[lane] : 0;
#pragma unroll
      for (int s = 1; s < 16; s <<= 1) {
        int u = __shfl_up(t, s);
        if (lane >= s) t += u;
      }
      if (lane < 16) wsum[lane] = t;
    }
    __syncthreads();
    int wbase = (wv > 0) ? wsum[wv - 1] : 0;
    if (i < N_NODES) off[i] = carry_s + wbase + v - orig;
    __syncthreads();
    if (threadIdx.x == 1023) carry_s += wsum[15];
    __syncthreads();
  }
  if (threadIdx.x == 0) off[N_NODES] = carry_s;
}

__global__ void scatter_edges(const int* __restrict__ src, const int* __restrict__ dst,
                              int* __restrict__ cursor, int* __restrict__ csr_src,
                              int* __restrict__ csr_eid) {
  int e = blockIdx.x * 256 + threadIdx.x;
  if (e >= N_EDGES) return;
  int d = dst[e];
  int pos = atomicAdd(cursor + d, 1);
  csr_src[pos] = src[e];
  csr_eid[pos] = e;
}

// ---------------- per-layer kernels ----------------
// hb = bf16(relu(x @ W_pn + b_pn)), zero-padded [NPAD][KPAD]
__global__ void proj_nodes(const float* __restrict__ x, const float* __restrict__ Wpn,
                           const float* __restrict__ bpn, ushort_t* __restrict__ hb) {
  unsigned f = blockIdx.x * 256u + threadIdx.x;
  if (f >= (unsigned)NPAD * KPAD) return;
  unsigned n = f / KPAD, hh = f % KPAD;
  float v = 0.f;
  if (n < N_NODES && hh < H_) {
    float acc = bpn[hh];
    const float* xr = x + n * DIN_;
    const float* wc = Wpn + hh;
#pragma unroll 8
    for (int k = 0; k < DIN_; ++k) acc += xr[k] * wc[k * H_];
    v = fmaxf(acc, 0.f);
  }
  hb[f] = f2b(v);
}

// zb[n][t] = bf16( hb[n][t] + sum_{p in CSR(n)} relu(hb[src_p][t] + (ea[eid_p]@Wpe+bpe)[t]) )
// One block per node (incl. pad nodes -> zero row). 320 threads = 5 waves;
// each wave owns feature chunk t = threadIdx.x. Wpe column held in 16 NAMED
// scalar registers (no array -> no scratch). Edge loop is wave-uniform so
// csr/ea reads become scalar loads.
__global__ __launch_bounds__(320) void node_agg_wave(const ushort_t* __restrict__ hb,
                                                     const float* __restrict__ ea,
                                                     const float* __restrict__ Wpe,
                                                     const float* __restrict__ bpe,
                                                     const int* __restrict__ csr_src,
                                                     const int* __restrict__ csr_eid,
                                                     const int* __restrict__ off,
                                                     ushort_t* __restrict__ zb) {
  int n = blockIdx.x;
  int t = threadIdx.x;  // 0..319, wave w covers [w*64, w*64+64)
  unsigned zi = (unsigned)n * KPAD + t;
  if (n >= N_NODES) {
    zb[zi] = 0;
    return;
  }
  int p0 = __builtin_amdgcn_readfirstlane(off[n]);
  int p1 = __builtin_amdgcn_readfirstlane(off[n + 1]);
  bool act = (t < H_);
  float acc = b2f(hb[zi]);  // self term (pad cols are stored 0)
  float bb = act ? bpe[t] : 0.f;
#define LDW(K) float w##K = act ? Wpe[(K) * H_ + t] : 0.f;
  LDW(0) LDW(1) LDW(2) LDW(3) LDW(4) LDW(5) LDW(6) LDW(7)
  LDW(8) LDW(9) LDW(10) LDW(11) LDW(12) LDW(13) LDW(14) LDW(15)
#undef LDW
  for (int p = p0; p < p1; ++p) {
    int sid = __builtin_amdgcn_readfirstlane(csr_src[p]);
    int eid = __builtin_amdgcn_readfirstlane(csr_eid[p]);
    float g = b2f(hb[(unsigned)sid * KPAD + t]);  // issue gather first
    const float* ar = ea + (size_t)eid * EIN_;
    float d = bb;
    d += ar[0] * w0;   d += ar[1] * w1;   d += ar[2] * w2;   d += ar[3] * w3;
    d += ar[4] * w4;   d += ar[5] * w5;   d += ar[6] * w6;   d += ar[7] * w7;
    d += ar[8] * w8;   d += ar[9] * w9;   d += ar[10] * w10; d += ar[11] * w11;
    d += ar[12] * w12; d += ar[13] * w13; d += ar[14] * w14; d += ar[15] * w15;
    acc += fmaxf(g + d, 0.f);
  }
  zb[zi] = f2b(acc);
}

// C = act(A @ W + bias).  A: bf16 [NPAD][320].  Bp: frag-packed bf16 [40][320][8].
// OUT_BF16: write bf16 [NPAD][320] (pad cols = 0); else fp32 [N][300].
template <int RELU_OUT, int OUT_BF16>
__global__ __launch_bounds__(256) void gemm300(const ushort_t* __restrict__ A,
                                               const ushort_t* __restrict__ Bp,
                                               const float* __restrict__ bias,
                                               void* __restrict__ Cout) {
  int lane = threadIdx.x & 63;
  int wid  = threadIdx.x >> 6;
  int lr = lane & 15, lg = lane >> 4;
  int rowblk  = blockIdx.x * 64 + (wid & 1) * 32;  // wave: 32 rows x 160 cols
  int colbase = (wid >> 1) * 160;
  f32x4 acc[2][10];
#pragma unroll
  for (int a = 0; a < 2; ++a)
#pragma unroll
    for (int c = 0; c < 10; ++c) acc[a][c] = (f32x4){0.f, 0.f, 0.f, 0.f};

  const ushort_t* Ap = A + (unsigned)(rowblk + lr) * KPAD + lg * 8;
  for (int k0 = 0; k0 < KPAD; k0 += 32) {
    bf16x8 a0 = *(const bf16x8*)(Ap + k0);
    bf16x8 a1 = *(const bf16x8*)(Ap + 16 * KPAD + k0);
    const ushort_t* bb = Bp + ((unsigned)(k0 / 8 + lg) * KPAD + colbase + lr) * 8;
#pragma unroll
    for (int c = 0; c < 10; ++c) {
      bf16x8 b = *(const bf16x8*)(bb + c * 16 * 8);
      acc[0][c] = __builtin_amdgcn_mfma_f32_16x16x32_bf16(a0, b, acc[0][c], 0, 0, 0);
      acc[1][c] = __builtin_amdgcn_mfma_f32_16x16x32_bf16(a1, b, acc[1][c], 0, 0, 0);
    }
  }
  // epilogue: D mapping col=lane&15, row=(lane>>4)*4+r  [m89/m91]
#pragma unroll
  for (int rt = 0; rt < 2; ++rt) {
#pragma unroll
    for (int c = 0; c < 10; ++c) {
      int col = colbase + c * 16 + lr;
      float bv = (col < H_) ? bias[col] : 0.f;
#pragma unroll
      for (int r = 0; r < 4; ++r) {
        int row = rowblk + rt * 16 + lg * 4 + r;
        if (row >= N_NODES) continue;
        float v = acc[rt][c][r] + bv;
        if (RELU_OUT) v = fmaxf(v, 0.f);
        if (OUT_BF16) {
          ((ushort_t*)Cout)[(unsigned)row * KPAD + col] = f2b(v);
        } else if (col < H_) {
          ((float*)Cout)[(unsigned)row * H_ + col] = v;
        }
      }
    }
  }
}

// pooled[g] = sum of h rows with batch==g (batch sorted -> binary search bounds)
__global__ void pool_kernel(const float* __restrict__ h, const int* __restrict__ batch,
                            float* __restrict__ pooled) {
  int g = blockIdx.x;
  int hh = threadIdx.x;  // block 320
  int lo = 0, hi = N_NODES;
  while (lo < hi) { int mid = (lo + hi) >> 1; if (batch[mid] < g) lo = mid + 1; else hi = mid; }
  int start = lo;
  hi = N_NODES;
  while (lo < hi) { int mid = (lo + hi) >> 1; if (batch[mid] < g + 1) lo = mid + 1; else hi = mid; }
  int end = lo;
  if (hh >= H_) return;
  float s = 0.f;
  for (int n = start; n < end; ++n) s += h[(unsigned)n * H_ + hh];
  pooled[g * H_ + hh] = s;
}

// out = prelu(pooled @ W_sp + b_sp)
__global__ void final_kernel(const float* __restrict__ pooled, const float* __restrict__ Wsp,
                             const float* __restrict__ bsp, const float* __restrict__ pa,
                             float* __restrict__ out) {
  int f = blockIdx.x * 256 + threadIdx.x;
  if (f >= G_GR * R_OUT) return;
  int g = f >> 10, r = f & 1023;
  float acc = bsp[r];
  const float* pr = pooled + g * H_;
  const float* wc = Wsp + r;
  for (int k = 0; k < H_; ++k) acc += pr[k] * wc[k * R_OUT];
  float a = pa[0];
  out[f] = acc >= 0.f ? acc : a * acc;
}

extern "C" void kernel_launch(void* const* d_in, const int* in_sizes, int n_in,
                              void* d_out, int out_size, void* d_ws, size_t ws_size,
                              hipStream_t stream) {
  const float* x   = (const float*)d_in[0];
  const float* ea  = (const float*)d_in[1];
  const int*   ei  = (const int*)d_in[2];
  const int*   bat = (const int*)d_in[3];
  const float* Wpn = (const float*)d_in[4];
  const float* bpn = (const float*)d_in[5];
  const float* Wpe = (const float*)d_in[6];
  const float* bpe = (const float*)d_in[7];
  const float* W1  = (const float*)d_in[8];
  const float* b1  = (const float*)d_in[9];
  const float* W2  = (const float*)d_in[10];
  const float* b2  = (const float*)d_in[11];
  const float* Wsp = (const float*)d_in[12];
  const float* bsp = (const float*)d_in[13];
  const float* pa  = (const float*)d_in[14];
  const int* src = ei;
  const int* dst = ei + N_EDGES;

  char* ws = (char*)d_ws;
  size_t off_b = 0;
  auto alloc = [&](size_t bytes) {
    void* p = ws + off_b;
    off_b += (bytes + 255) & ~(size_t)255;
    return p;
  };
  ushort_t* hb      = (ushort_t*)alloc(sizeof(ushort_t) * (size_t)NPAD * KPAD);
  ushort_t* zb      = (ushort_t*)alloc(sizeof(ushort_t) * (size_t)NPAD * KPAD);
  ushort_t* tb      = (ushort_t*)alloc(sizeof(ushort_t) * (size_t)NPAD * KPAD);
  float*    h       = (float*)alloc(sizeof(float) * (size_t)N_NODES * H_);
  ushort_t* Bp1     = (ushort_t*)alloc(sizeof(ushort_t) * (size_t)DEPTH_ * 40 * KPAD * 8);
  ushort_t* Bp2     = (ushort_t*)alloc(sizeof(ushort_t) * (size_t)DEPTH_ * 40 * KPAD * 8);
  float*    pooled  = (float*)alloc(sizeof(float) * (size_t)G_GR * H_);
  int*      deg     = (int*)alloc(sizeof(int) * N_NODES);
  int*      offs    = (int*)alloc(sizeof(int) * (N_NODES + 1));
  int*      cursor  = (int*)alloc(sizeof(int) * N_NODES);
  int*      csr_src = (int*)alloc(sizeof(int) * N_EDGES);
  int*      csr_eid = (int*)alloc(sizeof(int) * N_EDGES);

  // ---- CSR build ----
  hipMemsetAsync(deg, 0, sizeof(int) * N_NODES, stream);
  hist_deg<<<(N_EDGES + 255) / 256, 256, 0, stream>>>(dst, deg);
  exscan_kernel<<<1, 1024, 0, stream>>>(deg, offs);
  hipMemcpyAsync(cursor, offs, sizeof(int) * N_NODES, hipMemcpyDeviceToDevice, stream);
  scatter_edges<<<(N_EDGES + 255) / 256, 256, 0, stream>>>(src, dst, cursor, csr_src, csr_eid);

  pack_weights<<<(2 * DEPTH_ * 40 * KPAD * 8 + 255) / 256, 256, 0, stream>>>(W1, W2, Bp1, Bp2);
  proj_nodes<<<((unsigned)NPAD * KPAD + 255) / 256, 256, 0, stream>>>(x, Wpn, bpn, hb);

  for (int i = 0; i < DEPTH_; ++i) {
    node_agg_wave<<<NPAD, 320, 0, stream>>>(hb, ea, Wpe, bpe, csr_src, csr_eid, offs, zb);
    gemm300<1, 1><<<NPAD / 64, 256, 0, stream>>>(zb, Bp1 + (size_t)i * 40 * KPAD * 8, b1 + i * H_, tb);
    if (i < DEPTH_ - 1)
      gemm300<1, 1><<<NPAD / 64, 256, 0, stream>>>(tb, Bp2 + (size_t)i * 40 * KPAD * 8, b2 + i * H_, hb);
    else
      gemm300<0, 0><<<NPAD / 64, 256, 0, stream>>>(tb, Bp2 + (size_t)i * 40 * KPAD * 8, b2 + i * H_, h);
  }

  pool_kernel<<<G_GR, 320, 0, stream>>>(h, bat, pooled);
  final_kernel<<<(G_GR * R_OUT) / 256, 256, 0, stream>>>(pooled, Wsp, bsp, pa, (float*)d_out);
}

// Round 6
// 2362.060 us; speedup vs baseline: 1.1686x; 1.1686x over previous
//
#include <hip/hip_runtime.h>
#include <hip/hip_bf16.h>

#define N_NODES 50000
#define N_EDGES 800000
#define DIN_    64
#define EIN_    16
#define H_      300
#define R_OUT   1024
#define G_GR    256
#define DEPTH_  5
#define KPAD    320
#define NPAD    50048   // multiple of 64 >= N_NODES

typedef unsigned short ushort_t;
typedef __attribute__((ext_vector_type(8))) short bf16x8;
typedef __attribute__((ext_vector_type(4))) float f32x4;

__device__ __forceinline__ ushort_t f2b(float f) {
  unsigned x = __float_as_uint(f);
  unsigned r = (x + 0x7fffu + ((x >> 16) & 1u)) >> 16;  // RTN-even
  return (ushort_t)r;
}
__device__ __forceinline__ float b2f(ushort_t u) {
  return __uint_as_float((unsigned)u << 16);
}

// ---------------- weight packing (once per call) ----------------
// Pack W1/W2 (fp32 [DEPTH][300][300], k-major) into bf16 frag layout
// Bp[i][kg][n][j] , k = kg*8+j, zero-padded to 320x320.
__global__ void pack_weights(const float* __restrict__ W1, const float* __restrict__ W2,
                             ushort_t* __restrict__ Bp1, ushort_t* __restrict__ Bp2) {
  int idx = blockIdx.x * 256 + threadIdx.x;
  const int per = DEPTH_ * 40 * KPAD * 8;  // 512000
  if (idx >= 2 * per) return;
  const float* W = W1;
  ushort_t* Bp = Bp1;
  int t = idx;
  if (t >= per) { t -= per; W = W2; Bp = Bp2; }
  int j  = t & 7;
  int n  = (t >> 3) % KPAD;
  int kg = ((t >> 3) / KPAD) % 40;
  int i  = t / (40 * KPAD * 8);
  int k  = kg * 8 + j;
  float v = (k < H_ && n < H_) ? W[(i * H_ + k) * H_ + n] : 0.f;
  Bp[t] = f2b(v);
}

// Pack Wpe (fp32 [16][300]) into frag layout Bpe[kg<4][n<320][j<8], K padded to 32
__global__ void pack_wpe(const float* __restrict__ Wpe, ushort_t* __restrict__ Bpe) {
  int t = blockIdx.x * 256 + threadIdx.x;
  if (t >= 4 * KPAD * 8) return;
  int j  = t & 7;
  int n  = (t >> 3) % KPAD;
  int kg = (t >> 3) / KPAD;
  int k  = kg * 8 + j;
  float v = (k < EIN_ && n < H_) ? Wpe[k * H_ + n] : 0.f;
  Bpe[t] = f2b(v);
}

// ---------------- CSR build (once per call) ----------------
__global__ void hist_deg(const int* __restrict__ dst, int* __restrict__ deg) {
  int e = blockIdx.x * 256 + threadIdx.x;
  if (e < N_EDGES) atomicAdd(deg + dst[e], 1);
}

// single-block exclusive scan of deg[0..N_NODES) -> off, off[N_NODES]=total
__global__ __launch_bounds__(1024) void exscan_kernel(const int* __restrict__ deg,
                                                      int* __restrict__ off) {
  __shared__ int wsum[16];
  __shared__ int carry_s;
  int lane = threadIdx.x & 63;
  int wv = threadIdx.x >> 6;
  if (threadIdx.x == 0) carry_s = 0;
  __syncthreads();
  for (int base = 0; base < N_NODES; base += 1024) {
    int i = base + (int)threadIdx.x;
    int orig = (i < N_NODES) ? deg[i] : 0;
    int v = orig;
#pragma unroll
    for (int s = 1; s < 64; s <<= 1) {
      int u = __shfl_up(v, s);
      if (lane >= s) v += u;
    }
    if (lane == 63) wsum[wv] = v;
    __syncthreads();
    if (wv == 0) {
      int t = (lane < 16) ? wsum[lane] : 0;
#pragma unroll
      for (int s = 1; s < 16; s <<= 1) {
        int u = __shfl_up(t, s);
        if (lane >= s) t += u;
      }
      if (lane < 16) wsum[lane] = t;
    }
    __syncthreads();
    int wbase = (wv > 0) ? wsum[wv - 1] : 0;
    if (i < N_NODES) off[i] = carry_s + wbase + v - orig;
    __syncthreads();
    if (threadIdx.x == 1023) carry_s += wsum[15];
    __syncthreads();
  }
  if (threadIdx.x == 0) off[N_NODES] = carry_s;
}

__global__ void scatter_edges(const int* __restrict__ src, const int* __restrict__ dst,
                              int* __restrict__ cursor, int* __restrict__ csr_src,
                              int* __restrict__ csr_eid) {
  int e = blockIdx.x * 256 + threadIdx.x;
  if (e >= N_EDGES) return;
  int d = dst[e];
  int pos = atomicAdd(cursor + d, 1);
  csr_src[pos] = src[e];
  csr_eid[pos] = e;
}

// ---------------- one-time e precompute (PRE path) ----------------
// e_csr[p][c] = bf16( (ea[eid_p] @ Wpe + bpe)[c] ), tight [N_EDGES][300].
// K=32 (padded), one MFMA k-step. Wave: 32 rows x 160 cols; block 256 -> 64 rows.
__global__ __launch_bounds__(256) void e_gemm(const float* __restrict__ ea,
                                              const int* __restrict__ csr_eid,
                                              const ushort_t* __restrict__ Bpe,
                                              const float* __restrict__ bpe,
                                              ushort_t* __restrict__ e_csr) {
  int lane = threadIdx.x & 63;
  int wid  = threadIdx.x >> 6;
  int lr = lane & 15, lg = lane >> 4;
  int rowblk  = blockIdx.x * 64 + (wid & 1) * 32;
  int colbase = (wid >> 1) * 160;
  int eid0 = csr_eid[rowblk + lr];
  int eid1 = csr_eid[rowblk + 16 + lr];
  bf16x8 a0 = (bf16x8){0, 0, 0, 0, 0, 0, 0, 0};
  bf16x8 a1 = a0;
  if (lg < 2) {
    const float* ar0 = ea + (size_t)eid0 * EIN_ + lg * 8;
    const float* ar1 = ea + (size_t)eid1 * EIN_ + lg * 8;
    f32x4 l0 = *(const f32x4*)ar0, h0 = *(const f32x4*)(ar0 + 4);
    f32x4 l1 = *(const f32x4*)ar1, h1 = *(const f32x4*)(ar1 + 4);
#pragma unroll
    for (int j = 0; j < 4; ++j) {
      a0[j] = (short)f2b(l0[j]); a0[j + 4] = (short)f2b(h0[j]);
      a1[j] = (short)f2b(l1[j]); a1[j + 4] = (short)f2b(h1[j]);
    }
  }
  const ushort_t* bb = Bpe + ((unsigned)lg * KPAD + colbase + lr) * 8;
  f32x4 acc[2][10];
#pragma unroll
  for (int a = 0; a < 2; ++a)
#pragma unroll
    for (int c = 0; c < 10; ++c) acc[a][c] = (f32x4){0.f, 0.f, 0.f, 0.f};
#pragma unroll
  for (int c = 0; c < 10; ++c) {
    bf16x8 b = *(const bf16x8*)(bb + c * 16 * 8);
    acc[0][c] = __builtin_amdgcn_mfma_f32_16x16x32_bf16(a0, b, acc[0][c], 0, 0, 0);
    acc[1][c] = __builtin_amdgcn_mfma_f32_16x16x32_bf16(a1, b, acc[1][c], 0, 0, 0);
  }
#pragma unroll
  for (int rt = 0; rt < 2; ++rt) {
#pragma unroll
    for (int c = 0; c < 10; ++c) {
      int col = colbase + c * 16 + lr;
      if (col >= H_) continue;
      float bv = bpe[col];
#pragma unroll
      for (int r = 0; r < 4; ++r) {
        int row = rowblk + rt * 16 + lg * 4 + r;
        e_csr[(size_t)row * H_ + col] = f2b(acc[rt][c][r] + bv);
      }
    }
  }
}

// ---------------- per-layer kernels ----------------
// hb = bf16(relu(x @ W_pn + b_pn)), zero-padded [NPAD][KPAD]
__global__ void proj_nodes(const float* __restrict__ x, const float* __restrict__ Wpn,
                           const float* __restrict__ bpn, ushort_t* __restrict__ hb) {
  unsigned f = blockIdx.x * 256u + threadIdx.x;
  if (f >= (unsigned)NPAD * KPAD) return;
  unsigned n = f / KPAD, hh = f % KPAD;
  float v = 0.f;
  if (n < N_NODES && hh < H_) {
    float acc = bpn[hh];
    const float* xr = x + n * DIN_;
    const float* wc = Wpn + hh;
#pragma unroll 8
    for (int k = 0; k < DIN_; ++k) acc += xr[k] * wc[k * H_];
    v = fmaxf(acc, 0.f);
  }
  hb[f] = f2b(v);
}

// zb[n][t] = bf16( hb[n][t] + sum_{p in CSR(n)} relu(hb[src_p][t] + e_csr[p][t]) )
__global__ __launch_bounds__(320) void node_agg_pre(const ushort_t* __restrict__ hb,
                                                    const ushort_t* __restrict__ e_csr,
                                                    const int* __restrict__ csr_src,
                                                    const int* __restrict__ off,
                                                    ushort_t* __restrict__ zb) {
  int n = blockIdx.x;
  int t = threadIdx.x;  // 0..319
  unsigned zi = (unsigned)n * KPAD + t;
  if (n >= N_NODES || t >= H_) {
    zb[zi] = 0;
    return;
  }
  int p0 = __builtin_amdgcn_readfirstlane(off[n]);
  int p1 = __builtin_amdgcn_readfirstlane(off[n + 1]);
  float acc = b2f(hb[zi]);  // self term
  int p = p0;
  for (; p + 4 <= p1; p += 4) {
    int s0 = csr_src[p], s1 = csr_src[p + 1], s2 = csr_src[p + 2], s3 = csr_src[p + 3];
    float e0 = b2f(e_csr[(size_t)p * H_ + t]);
    float e1 = b2f(e_csr[(size_t)(p + 1) * H_ + t]);
    float e2 = b2f(e_csr[(size_t)(p + 2) * H_ + t]);
    float e3 = b2f(e_csr[(size_t)(p + 3) * H_ + t]);
    float g0 = b2f(hb[(unsigned)s0 * KPAD + t]);
    float g1 = b2f(hb[(unsigned)s1 * KPAD + t]);
    float g2 = b2f(hb[(unsigned)s2 * KPAD + t]);
    float g3 = b2f(hb[(unsigned)s3 * KPAD + t]);
    acc += fmaxf(g0 + e0, 0.f);
    acc += fmaxf(g1 + e1, 0.f);
    acc += fmaxf(g2 + e2, 0.f);
    acc += fmaxf(g3 + e3, 0.f);
  }
  for (; p < p1; ++p) {
    int s = csr_src[p];
    float e = b2f(e_csr[(size_t)p * H_ + t]);
    float g = b2f(hb[(unsigned)s * KPAD + t]);
    acc += fmaxf(g + e, 0.f);
  }
  zb[zi] = f2b(acc);
}

// -------- fallback (small workspace): recompute e on the fly (R2 structure) --------
__device__ __forceinline__ float edot(const float* __restrict__ ar, const float* w) {
  f32x4 v0 = *(const f32x4*)ar;
  f32x4 v1 = *(const f32x4*)(ar + 4);
  f32x4 v2 = *(const f32x4*)(ar + 8);
  f32x4 v3 = *(const f32x4*)(ar + 12);
  float s = v0[0] * w[0] + v0[1] * w[1] + v0[2] * w[2] + v0[3] * w[3];
  s += v1[0] * w[4] + v1[1] * w[5] + v1[2] * w[6] + v1[3] * w[7];
  s += v2[0] * w[8] + v2[1] * w[9] + v2[2] * w[10] + v2[3] * w[11];
  s += v3[0] * w[12] + v3[1] * w[13] + v3[2] * w[14] + v3[3] * w[15];
  return s;
}

__global__ __launch_bounds__(320) void node_agg_fly(const ushort_t* __restrict__ hb,
                                                    const float* __restrict__ ea,
                                                    const float* __restrict__ Wpe,
                                                    const float* __restrict__ bpe,
                                                    const int* __restrict__ csr_src,
                                                    const int* __restrict__ csr_eid,
                                                    const int* __restrict__ off,
                                                    ushort_t* __restrict__ zb) {
  int n = blockIdx.x;
  int t = threadIdx.x;
  unsigned zi = (unsigned)n * KPAD + t;
  if (n >= N_NODES || t >= H_) {
    zb[zi] = 0;
    return;
  }
  int p0 = off[n], p1 = off[n + 1];
  float acc = b2f(hb[zi]);
  float w[EIN_];
#pragma unroll
  for (int k = 0; k < EIN_; ++k) w[k] = Wpe[k * H_ + t];
  float bb = bpe[t];
  int p = p0;
  for (; p + 4 <= p1; p += 4) {
    int s0 = csr_src[p], s1 = csr_src[p + 1], s2 = csr_src[p + 2], s3 = csr_src[p + 3];
    int e0 = csr_eid[p], e1 = csr_eid[p + 1], e2 = csr_eid[p + 2], e3 = csr_eid[p + 3];
    float g0 = b2f(hb[(unsigned)s0 * KPAD + t]);
    float g1 = b2f(hb[(unsigned)s1 * KPAD + t]);
    float g2 = b2f(hb[(unsigned)s2 * KPAD + t]);
    float g3 = b2f(hb[(unsigned)s3 * KPAD + t]);
    float d0 = edot(ea + (size_t)e0 * EIN_, w);
    float d1 = edot(ea + (size_t)e1 * EIN_, w);
    float d2 = edot(ea + (size_t)e2 * EIN_, w);
    float d3 = edot(ea + (size_t)e3 * EIN_, w);
    acc += fmaxf(g0 + d0 + bb, 0.f);
    acc += fmaxf(g1 + d1 + bb, 0.f);
    acc += fmaxf(g2 + d2 + bb, 0.f);
    acc += fmaxf(g3 + d3 + bb, 0.f);
  }
  for (; p < p1; ++p) {
    int s = csr_src[p];
    int e = csr_eid[p];
    float g = b2f(hb[(unsigned)s * KPAD + t]);
    float d = edot(ea + (size_t)e * EIN_, w);
    acc += fmaxf(g + d + bb, 0.f);
  }
  zb[zi] = f2b(acc);
}

// C = act(A @ W + bias).  A: bf16 [NPAD][320].  Bp: frag-packed bf16 [40][320][8].
// OUT_BF16: write bf16 [NPAD][320] (pad cols = 0); else fp32 [N][300].
// NOTE: supports in-place A==Cout (block b touches only rows [64b,64b+64);
// __syncthreads() separates all A-reads from C-writes). No __restrict__ on A/Cout.
template <int RELU_OUT, int OUT_BF16>
__global__ __launch_bounds__(256) void gemm300(const ushort_t* A,
                                               const ushort_t* __restrict__ Bp,
                                               const float* __restrict__ bias,
                                               void* Cout) {
  int lane = threadIdx.x & 63;
  int wid  = threadIdx.x >> 6;
  int lr = lane & 15, lg = lane >> 4;
  int rowblk  = blockIdx.x * 64 + (wid & 1) * 32;  // wave: 32 rows x 160 cols
  int colbase = (wid >> 1) * 160;
  f32x4 acc[2][10];
#pragma unroll
  for (int a = 0; a < 2; ++a)
#pragma unroll
    for (int c = 0; c < 10; ++c) acc[a][c] = (f32x4){0.f, 0.f, 0.f, 0.f};

  const ushort_t* Ap = A + (unsigned)(rowblk + lr) * KPAD + lg * 8;
  for (int k0 = 0; k0 < KPAD; k0 += 32) {
    bf16x8 a0 = *(const bf16x8*)(Ap + k0);
    bf16x8 a1 = *(const bf16x8*)(Ap + 16 * KPAD + k0);
    const ushort_t* bb = Bp + ((unsigned)(k0 / 8 + lg) * KPAD + colbase + lr) * 8;
#pragma unroll
    for (int c = 0; c < 10; ++c) {
      bf16x8 b = *(const bf16x8*)(bb + c * 16 * 8);
      acc[0][c] = __builtin_amdgcn_mfma_f32_16x16x32_bf16(a0, b, acc[0][c], 0, 0, 0);
      acc[1][c] = __builtin_amdgcn_mfma_f32_16x16x32_bf16(a1, b, acc[1][c], 0, 0, 0);
    }
  }
  __syncthreads();  // all A-reads done before any in-place C-write
  // epilogue: D mapping col=lane&15, row=(lane>>4)*4+r  [m89/m91]
#pragma unroll
  for (int rt = 0; rt < 2; ++rt) {
#pragma unroll
    for (int c = 0; c < 10; ++c) {
      int col = colbase + c * 16 + lr;
      float bv = (col < H_) ? bias[col] : 0.f;
#pragma unroll
      for (int r = 0; r < 4; ++r) {
        int row = rowblk + rt * 16 + lg * 4 + r;
        if (row >= N_NODES) continue;
        float v = acc[rt][c][r] + bv;
        if (RELU_OUT) v = fmaxf(v, 0.f);
        if (OUT_BF16) {
          ((ushort_t*)Cout)[(unsigned)row * KPAD + col] = f2b(v);
        } else if (col < H_) {
          ((float*)Cout)[(unsigned)row * H_ + col] = v;
        }
      }
    }
  }
}

// pooled[g] = sum of h rows with batch==g (batch sorted -> binary search bounds)
__global__ void pool_kernel(const float* __restrict__ h, const int* __restrict__ batch,
                            float* __restrict__ pooled) {
  int g = blockIdx.x;
  int hh = threadIdx.x;  // block 320
  int lo = 0, hi = N_NODES;
  while (lo < hi) { int mid = (lo + hi) >> 1; if (batch[mid] < g) lo = mid + 1; else hi = mid; }
  int start = lo;
  hi = N_NODES;
  while (lo < hi) { int mid = (lo + hi) >> 1; if (batch[mid] < g + 1) lo = mid + 1; else hi = mid; }
  int end = lo;
  if (hh >= H_) return;
  float s = 0.f;
  for (int n = start; n < end; ++n) s += h[(unsigned)n * H_ + hh];
  pooled[g * H_ + hh] = s;
}

// out = prelu(pooled @ W_sp + b_sp)
__global__ void final_kernel(const float* __restrict__ pooled, const float* __restrict__ Wsp,
                             const float* __restrict__ bsp, const float* __restrict__ pa,
                             float* __restrict__ out) {
  int f = blockIdx.x * 256 + threadIdx.x;
  if (f >= G_GR * R_OUT) return;
  int g = f >> 10, r = f & 1023;
  float acc = bsp[r];
  const float* pr = pooled + g * H_;
  const float* wc = Wsp + r;
  for (int k = 0; k < H_; ++k) acc += pr[k] * wc[k * R_OUT];
  float a = pa[0];
  out[f] = acc >= 0.f ? acc : a * acc;
}

extern "C" void kernel_launch(void* const* d_in, const int* in_sizes, int n_in,
                              void* d_out, int out_size, void* d_ws, size_t ws_size,
                              hipStream_t stream) {
  const float* x   = (const float*)d_in[0];
  const float* ea  = (const float*)d_in[1];
  const int*   ei  = (const int*)d_in[2];
  const int*   bat = (const int*)d_in[3];
  const float* Wpn = (const float*)d_in[4];
  const float* bpn = (const float*)d_in[5];
  const float* Wpe = (const float*)d_in[6];
  const float* bpe = (const float*)d_in[7];
  const float* W1  = (const float*)d_in[8];
  const float* b1  = (const float*)d_in[9];
  const float* W2  = (const float*)d_in[10];
  const float* b2  = (const float*)d_in[11];
  const float* Wsp = (const float*)d_in[12];
  const float* bsp = (const float*)d_in[13];
  const float* pa  = (const float*)d_in[14];
  const int* src = ei;
  const int* dst = ei + N_EDGES;

  char* ws = (char*)d_ws;
  size_t off_b = 0;
  auto alloc = [&](size_t bytes) {
    void* p = ws + off_b;
    off_b += (bytes + 255) & ~(size_t)255;
    return p;
  };
  ushort_t* hb      = (ushort_t*)alloc(sizeof(ushort_t) * (size_t)NPAD * KPAD);  // 32 MB
  ushort_t* zb      = (ushort_t*)alloc(sizeof(ushort_t) * (size_t)NPAD * KPAD);  // 32 MB
  ushort_t* Bp1     = (ushort_t*)alloc(sizeof(ushort_t) * (size_t)DEPTH_ * 40 * KPAD * 8);
  ushort_t* Bp2     = (ushort_t*)alloc(sizeof(ushort_t) * (size_t)DEPTH_ * 40 * KPAD * 8);
  ushort_t* Bpe     = (ushort_t*)alloc(sizeof(ushort_t) * (size_t)4 * KPAD * 8);
  float*    pooled  = (float*)alloc(sizeof(float) * (size_t)G_GR * H_);
  int*      deg     = (int*)alloc(sizeof(int) * N_NODES);
  int*      offs    = (int*)alloc(sizeof(int) * (N_NODES + 1));
  int*      cursor  = (int*)alloc(sizeof(int) * N_NODES);
  int*      csr_src = (int*)alloc(sizeof(int) * N_EDGES);
  int*      csr_eid = (int*)alloc(sizeof(int) * N_EDGES);
  // e_csr (PRE path) aliases with the fp32 h output buffer: e_csr is dead after
  // the last node_agg, before the final gemm writes h. Same addresses every call.
  char*     big     = (char*)alloc(sizeof(ushort_t) * (size_t)N_EDGES * H_);  // 480 MB
  ushort_t* e_csr   = (ushort_t*)big;
  float*    h       = (float*)big;  // 60 MB, fits inside big
  const bool PRE = (off_b <= ws_size);  // constant across calls -> graph-safe
  if (!PRE) {
    // fallback only needs h (60 MB) in the big slot; guaranteed since base~73MB+60MB < 215MB
  }

  // ---- CSR build ----
  hipMemsetAsync(deg, 0, sizeof(int) * N_NODES, stream);
  hist_deg<<<(N_EDGES + 255) / 256, 256, 0, stream>>>(dst, deg);
  exscan_kernel<<<1, 1024, 0, stream>>>(deg, offs);
  hipMemcpyAsync(cursor, offs, sizeof(int) * N_NODES, hipMemcpyDeviceToDevice, stream);
  scatter_edges<<<(N_EDGES + 255) / 256, 256, 0, stream>>>(src, dst, cursor, csr_src, csr_eid);

  pack_weights<<<(2 * DEPTH_ * 40 * KPAD * 8 + 255) / 256, 256, 0, stream>>>(W1, W2, Bp1, Bp2);
  proj_nodes<<<((unsigned)NPAD * KPAD + 255) / 256, 256, 0, stream>>>(x, Wpn, bpn, hb);

  if (PRE) {
    pack_wpe<<<(4 * KPAD * 8 + 255) / 256, 256, 0, stream>>>(Wpe, Bpe);
    e_gemm<<<N_EDGES / 64, 256, 0, stream>>>(ea, csr_eid, Bpe, bpe, e_csr);
  }

  for (int i = 0; i < DEPTH_; ++i) {
    if (PRE)
      node_agg_pre<<<NPAD, 320, 0, stream>>>(hb, e_csr, csr_src, offs, zb);
    else
      node_agg_fly<<<NPAD, 320, 0, stream>>>(hb, ea, Wpe, bpe, csr_src, csr_eid, offs, zb);
    // in-place: zb = relu(zb @ W1 + b1)
    gemm300<1, 1><<<NPAD / 64, 256, 0, stream>>>(zb, Bp1 + (size_t)i * 40 * KPAD * 8, b1 + i * H_, zb);
    if (i < DEPTH_ - 1)
      gemm300<1, 1><<<NPAD / 64, 256, 0, stream>>>(zb, Bp2 + (size_t)i * 40 * KPAD * 8, b2 + i * H_, hb);
    else
      gemm300<0, 0><<<NPAD / 64, 256, 0, stream>>>(zb, Bp2 + (size_t)i * 40 * KPAD * 8, b2 + i * H_, h);
  }

  pool_kernel<<<G_GR, 320, 0, stream>>>(h, bat, pooled);
  final_kernel<<<(G_GR * R_OUT) / 256, 256, 0, stream>>>(pooled, Wsp, bsp, pa, (float*)d_out);
}

// Round 7
// 2200.436 us; speedup vs baseline: 1.2545x; 1.0735x over previous
//
#include <hip/hip_runtime.h>
#include <hip/hip_bf16.h>

#define N_NODES 50000
#define N_EDGES 800000
#define DIN_    64
#define EIN_    16
#define H_      300
#define R_OUT   1024
#define G_GR    256
#define DEPTH_  5
#define KPAD    320
#define NPAD    50048   // multiple of 64 >= N_NODES

typedef unsigned short ushort_t;
typedef __attribute__((ext_vector_type(8))) short bf16x8;
typedef __attribute__((ext_vector_type(4))) float f32x4;

__device__ __forceinline__ ushort_t f2b(float f) {
  unsigned x = __float_as_uint(f);
  unsigned r = (x + 0x7fffu + ((x >> 16) & 1u)) >> 16;  // RTN-even
  return (ushort_t)r;
}
__device__ __forceinline__ float b2f(ushort_t u) {
  return __uint_as_float((unsigned)u << 16);
}

// ---------------- weight packing (once per call) ----------------
// Pack W1/W2 (fp32 [DEPTH][300][300], k-major) into bf16 frag layout
// Bp[i][kg][n][j] , k = kg*8+j, zero-padded to 320x320.
__global__ void pack_weights(const float* __restrict__ W1, const float* __restrict__ W2,
                             ushort_t* __restrict__ Bp1, ushort_t* __restrict__ Bp2) {
  int idx = blockIdx.x * 256 + threadIdx.x;
  const int per = DEPTH_ * 40 * KPAD * 8;  // 512000
  if (idx >= 2 * per) return;
  const float* W = W1;
  ushort_t* Bp = Bp1;
  int t = idx;
  if (t >= per) { t -= per; W = W2; Bp = Bp2; }
  int j  = t & 7;
  int n  = (t >> 3) % KPAD;
  int kg = ((t >> 3) / KPAD) % 40;
  int i  = t / (40 * KPAD * 8);
  int k  = kg * 8 + j;
  float v = (k < H_ && n < H_) ? W[(i * H_ + k) * H_ + n] : 0.f;
  Bp[t] = f2b(v);
}

// Pack Wpe (fp32 [16][300]) + bpe into frag layout Bpe[kg<4][n<320][j<8],
// K padded to 32 with k==16 row = bpe (bias folded via A k=16 element = 1.0).
__global__ void pack_wpe(const float* __restrict__ Wpe, const float* __restrict__ bpe,
                         ushort_t* __restrict__ Bpe) {
  int t = blockIdx.x * 256 + threadIdx.x;
  if (t >= 4 * KPAD * 8) return;
  int j  = t & 7;
  int n  = (t >> 3) % KPAD;
  int kg = (t >> 3) / KPAD;
  int k  = kg * 8 + j;
  float v = 0.f;
  if (n < H_) {
    if (k < EIN_) v = Wpe[k * H_ + n];
    else if (k == EIN_) v = bpe[n];
  }
  Bpe[t] = f2b(v);
}

// ---------------- CSR build (once per call) ----------------
__global__ void hist_deg(const int* __restrict__ dst, int* __restrict__ deg) {
  int e = blockIdx.x * 256 + threadIdx.x;
  if (e < N_EDGES) atomicAdd(deg + dst[e], 1);
}

// single-block exclusive scan of deg[0..N_NODES) -> off, off[N_NODES]=total
__global__ __launch_bounds__(1024) void exscan_kernel(const int* __restrict__ deg,
                                                      int* __restrict__ off) {
  __shared__ int wsum[16];
  __shared__ int carry_s;
  int lane = threadIdx.x & 63;
  int wv = threadIdx.x >> 6;
  if (threadIdx.x == 0) carry_s = 0;
  __syncthreads();
  for (int base = 0; base < N_NODES; base += 1024) {
    int i = base + (int)threadIdx.x;
    int orig = (i < N_NODES) ? deg[i] : 0;
    int v = orig;
#pragma unroll
    for (int s = 1; s < 64; s <<= 1) {
      int u = __shfl_up(v, s);
      if (lane >= s) v += u;
    }
    if (lane == 63) wsum[wv] = v;
    __syncthreads();
    if (wv == 0) {
      int t = (lane < 16) ? wsum[lane] : 0;
#pragma unroll
      for (int s = 1; s < 16; s <<= 1) {
        int u = __shfl_up(t, s);
        if (lane >= s) t += u;
      }
      if (lane < 16) wsum[lane] = t;
    }
    __syncthreads();
    int wbase = (wv > 0) ? wsum[wv - 1] : 0;
    if (i < N_NODES) off[i] = carry_s + wbase + v - orig;
    __syncthreads();
    if (threadIdx.x == 1023) carry_s += wsum[15];
    __syncthreads();
  }
  if (threadIdx.x == 0) off[N_NODES] = carry_s;
}

__global__ void scatter_edges(const int* __restrict__ src, const int* __restrict__ dst,
                              int* __restrict__ cursor, int* __restrict__ csr_src,
                              int* __restrict__ csr_eid) {
  int e = blockIdx.x * 256 + threadIdx.x;
  if (e >= N_EDGES) return;
  int d = dst[e];
  int pos = atomicAdd(cursor + d, 1);
  csr_src[pos] = src[e];
  csr_eid[pos] = e;
}

// ---------------- per-layer kernels ----------------
// hb = bf16(relu(x @ W_pn + b_pn)), zero-padded [NPAD][KPAD]
__global__ void proj_nodes(const float* __restrict__ x, const float* __restrict__ Wpn,
                           const float* __restrict__ bpn, ushort_t* __restrict__ hb) {
  unsigned f = blockIdx.x * 256u + threadIdx.x;
  if (f >= (unsigned)NPAD * KPAD) return;
  unsigned n = f / KPAD, hh = f % KPAD;
  float v = 0.f;
  if (n < N_NODES && hh < H_) {
    float acc = bpn[hh];
    const float* xr = x + n * DIN_;
    const float* wc = Wpn + hh;
#pragma unroll 8
    for (int k = 0; k < DIN_; ++k) acc += xr[k] * wc[k * H_];
    v = fmaxf(acc, 0.f);
  }
  hb[f] = f2b(v);
}

// zb[n][t] = bf16( hb[n][t] + sum_{p in CSR(n)} relu(hb[src_p][t] + (ea[eid_p]@Wpe+bpe)[t]) )
// e-MLP computed via MFMA per 16-edge chunk. Block = 1 node, 320 thr = 5 waves.
// Wave w owns cols [64w, 64w+64) = 4 tiles of 16. A-frag: 16 ea rows (K=16 pad 32,
// k==16 row is 1.0 -> bias from Bpe). C-layout: col=lane&15, edge=(lane>>4)*4+r.
// csr_src/csr_eid must be padded with >=16 zero entries past N_EDGES.
__global__ __launch_bounds__(320) void node_agg_mfma(const ushort_t* __restrict__ hb,
                                                     const float* __restrict__ ea,
                                                     const ushort_t* __restrict__ Bpe,
                                                     const int* __restrict__ csr_src,
                                                     const int* __restrict__ csr_eid,
                                                     const int* __restrict__ off,
                                                     ushort_t* zb) {
  int n = blockIdx.x;
  int tid = threadIdx.x;
  if (n >= N_NODES) {
    zb[(unsigned)n * KPAD + tid] = 0;
    return;
  }
  int lane = tid & 63;
  int w = tid >> 6;  // wave 0..4
  int lr = lane & 15, lg = lane >> 4;
  int p0 = __builtin_amdgcn_readfirstlane(off[n]);
  int p1 = __builtin_amdgcn_readfirstlane(off[n + 1]);

  // B-frags for this wave's 4 col-tiles (wave-invariant across chunks)
  bf16x8 bfr[4];
#pragma unroll
  for (int t = 0; t < 4; ++t) {
    int col = w * 64 + t * 16 + lr;
    bfr[t] = *(const bf16x8*)(Bpe + ((unsigned)lg * KPAD + col) * 8);
  }

  float msum0 = 0.f, msum1 = 0.f, msum2 = 0.f, msum3 = 0.f;

  for (int pc = p0; pc < p1; pc += 16) {
    // ---- A-frag: ea rows for up to 16 edges (padded arrays -> safe reads)
    int eid = csr_eid[pc + lr];
    bf16x8 afr = (bf16x8){0, 0, 0, 0, 0, 0, 0, 0};
    if (lg < 2) {
      const float* ar = ea + (size_t)eid * EIN_ + lg * 8;
      f32x4 lo = *(const f32x4*)ar;
      f32x4 hi = *(const f32x4*)(ar + 4);
#pragma unroll
      for (int j = 0; j < 4; ++j) {
        afr[j] = (short)f2b(lo[j]);
        afr[j + 4] = (short)f2b(hi[j]);
      }
    } else if (lg == 2) {
      afr[0] = (short)0x3F80;  // k==16 -> 1.0 (bias row selector)
    }
    // ---- src ids for this lane's 4 edges (wave-uniform per lg group)
    int base = pc + 4 * lg;
    int s0 = csr_src[base + 0];
    int s1 = csr_src[base + 1];
    int s2 = csr_src[base + 2];
    int s3 = csr_src[base + 3];
    bool v0 = (base + 0 < p1), v1 = (base + 1 < p1), v2 = (base + 2 < p1), v3 = (base + 3 < p1);
#pragma unroll
    for (int t = 0; t < 4; ++t) {
      int colb = w * 64 + t * 16 + lr;
      // issue gathers early
      float g0 = b2f(hb[(unsigned)s0 * KPAD + colb]);
      float g1 = b2f(hb[(unsigned)s1 * KPAD + colb]);
      float g2 = b2f(hb[(unsigned)s2 * KPAD + colb]);
      float g3 = b2f(hb[(unsigned)s3 * KPAD + colb]);
      f32x4 e4 = __builtin_amdgcn_mfma_f32_16x16x32_bf16(afr, bfr[t], (f32x4){0.f, 0.f, 0.f, 0.f}, 0, 0, 0);
      float m0 = v0 ? fmaxf(g0 + e4[0], 0.f) : 0.f;
      float m1 = v1 ? fmaxf(g1 + e4[1], 0.f) : 0.f;
      float m2 = v2 ? fmaxf(g2 + e4[2], 0.f) : 0.f;
      float m3 = v3 ? fmaxf(g3 + e4[3], 0.f) : 0.f;
      float add = (m0 + m1) + (m2 + m3);
      if (t == 0) msum0 += add;
      else if (t == 1) msum1 += add;
      else if (t == 2) msum2 += add;
      else msum3 += add;
    }
  }

  // fold the 4 edge-groups (lg) per column, add self term, write
#pragma unroll
  for (int t = 0; t < 4; ++t) {
    float v = (t == 0) ? msum0 : (t == 1) ? msum1 : (t == 2) ? msum2 : msum3;
    v += __shfl_xor(v, 16);
    v += __shfl_xor(v, 32);
    if (lane < 16) {
      unsigned zi = (unsigned)n * KPAD + w * 64 + t * 16 + lane;
      zb[zi] = f2b(b2f(hb[zi]) + v);
    }
  }
}

// C = act(A @ W + bias).  A: bf16 [NPAD][320].  Bp: frag-packed bf16 [40][320][8].
// OUT_BF16: write bf16 [NPAD][320] (pad cols = 0); else fp32 [N][300].
// Supports in-place A==Cout (block b touches only rows [64b,64b+64);
// __syncthreads() separates all A-reads from C-writes).
template <int RELU_OUT, int OUT_BF16>
__global__ __launch_bounds__(256) void gemm300(const ushort_t* A,
                                               const ushort_t* __restrict__ Bp,
                                               const float* __restrict__ bias,
                                               void* Cout) {
  int lane = threadIdx.x & 63;
  int wid  = threadIdx.x >> 6;
  int lr = lane & 15, lg = lane >> 4;
  int rowblk  = blockIdx.x * 64 + (wid & 1) * 32;  // wave: 32 rows x 160 cols
  int colbase = (wid >> 1) * 160;
  f32x4 acc[2][10];
#pragma unroll
  for (int a = 0; a < 2; ++a)
#pragma unroll
    for (int c = 0; c < 10; ++c) acc[a][c] = (f32x4){0.f, 0.f, 0.f, 0.f};

  const ushort_t* Ap = A + (unsigned)(rowblk + lr) * KPAD + lg * 8;
  for (int k0 = 0; k0 < KPAD; k0 += 32) {
    bf16x8 a0 = *(const bf16x8*)(Ap + k0);
    bf16x8 a1 = *(const bf16x8*)(Ap + 16 * KPAD + k0);
    const ushort_t* bb = Bp + ((unsigned)(k0 / 8 + lg) * KPAD + colbase + lr) * 8;
#pragma unroll
    for (int c = 0; c < 10; ++c) {
      bf16x8 b = *(const bf16x8*)(bb + c * 16 * 8);
      acc[0][c] = __builtin_amdgcn_mfma_f32_16x16x32_bf16(a0, b, acc[0][c], 0, 0, 0);
      acc[1][c] = __builtin_amdgcn_mfma_f32_16x16x32_bf16(a1, b, acc[1][c], 0, 0, 0);
    }
  }
  __syncthreads();  // all A-reads done before any in-place C-write
  // epilogue: D mapping col=lane&15, row=(lane>>4)*4+r  [m89/m91]
#pragma unroll
  for (int rt = 0; rt < 2; ++rt) {
#pragma unroll
    for (int c = 0; c < 10; ++c) {
      int col = colbase + c * 16 + lr;
      float bv = (col < H_) ? bias[col] : 0.f;
#pragma unroll
      for (int r = 0; r < 4; ++r) {
        int row = rowblk + rt * 16 + lg * 4 + r;
        if (row >= N_NODES) continue;
        float v = acc[rt][c][r] + bv;
        if (RELU_OUT) v = fmaxf(v, 0.f);
        if (OUT_BF16) {
          ((ushort_t*)Cout)[(unsigned)row * KPAD + col] = f2b(v);
        } else if (col < H_) {
          ((float*)Cout)[(unsigned)row * H_ + col] = v;
        }
      }
    }
  }
}

// pooled[g] = sum of h rows with batch==g (batch sorted -> binary search bounds)
__global__ void pool_kernel(const float* __restrict__ h, const int* __restrict__ batch,
                            float* __restrict__ pooled) {
  int g = blockIdx.x;
  int hh = threadIdx.x;  // block 320
  int lo = 0, hi = N_NODES;
  while (lo < hi) { int mid = (lo + hi) >> 1; if (batch[mid] < g) lo = mid + 1; else hi = mid; }
  int start = lo;
  hi = N_NODES;
  while (lo < hi) { int mid = (lo + hi) >> 1; if (batch[mid] < g + 1) lo = mid + 1; else hi = mid; }
  int end = lo;
  if (hh >= H_) return;
  float s = 0.f;
  for (int n = start; n < end; ++n) s += h[(unsigned)n * H_ + hh];
  pooled[g * H_ + hh] = s;
}

// out = prelu(pooled @ W_sp + b_sp)
__global__ void final_kernel(const float* __restrict__ pooled, const float* __restrict__ Wsp,
                             const float* __restrict__ bsp, const float* __restrict__ pa,
                             float* __restrict__ out) {
  int f = blockIdx.x * 256 + threadIdx.x;
  if (f >= G_GR * R_OUT) return;
  int g = f >> 10, r = f & 1023;
  float acc = bsp[r];
  const float* pr = pooled + g * H_;
  const float* wc = Wsp + r;
  for (int k = 0; k < H_; ++k) acc += pr[k] * wc[k * R_OUT];
  float a = pa[0];
  out[f] = acc >= 0.f ? acc : a * acc;
}

extern "C" void kernel_launch(void* const* d_in, const int* in_sizes, int n_in,
                              void* d_out, int out_size, void* d_ws, size_t ws_size,
                              hipStream_t stream) {
  const float* x   = (const float*)d_in[0];
  const float* ea  = (const float*)d_in[1];
  const int*   ei  = (const int*)d_in[2];
  const int*   bat = (const int*)d_in[3];
  const float* Wpn = (const float*)d_in[4];
  const float* bpn = (const float*)d_in[5];
  const float* Wpe = (const float*)d_in[6];
  const float* bpe = (const float*)d_in[7];
  const float* W1  = (const float*)d_in[8];
  const float* b1  = (const float*)d_in[9];
  const float* W2  = (const float*)d_in[10];
  const float* b2  = (const float*)d_in[11];
  const float* Wsp = (const float*)d_in[12];
  const float* bsp = (const float*)d_in[13];
  const float* pa  = (const float*)d_in[14];
  const int* src = ei;
  const int* dst = ei + N_EDGES;

  char* ws = (char*)d_ws;
  size_t off_b = 0;
  auto alloc = [&](size_t bytes) {
    void* p = ws + off_b;
    off_b += (bytes + 255) & ~(size_t)255;
    return p;
  };
  ushort_t* hb      = (ushort_t*)alloc(sizeof(ushort_t) * (size_t)NPAD * KPAD);  // 32 MB
  ushort_t* zb      = (ushort_t*)alloc(sizeof(ushort_t) * (size_t)NPAD * KPAD);  // 32 MB
  float*    h       = (float*)alloc(sizeof(float) * (size_t)N_NODES * H_);       // 60 MB
  ushort_t* Bp1     = (ushort_t*)alloc(sizeof(ushort_t) * (size_t)DEPTH_ * 40 * KPAD * 8);
  ushort_t* Bp2     = (ushort_t*)alloc(sizeof(ushort_t) * (size_t)DEPTH_ * 40 * KPAD * 8);
  ushort_t* Bpe     = (ushort_t*)alloc(sizeof(ushort_t) * (size_t)4 * KPAD * 8);
  float*    pooled  = (float*)alloc(sizeof(float) * (size_t)G_GR * H_);
  int*      deg     = (int*)alloc(sizeof(int) * N_NODES);
  int*      offs    = (int*)alloc(sizeof(int) * (N_NODES + 1));
  int*      cursor  = (int*)alloc(sizeof(int) * N_NODES);
  int*      csr_src = (int*)alloc(sizeof(int) * (N_EDGES + 16));  // +16 zero pad
  int*      csr_eid = (int*)alloc(sizeof(int) * (N_EDGES + 16));  // +16 zero pad

  // ---- CSR build ----
  hipMemsetAsync(deg, 0, sizeof(int) * N_NODES, stream);
  hipMemsetAsync(csr_src + N_EDGES, 0, 16 * sizeof(int), stream);
  hipMemsetAsync(csr_eid + N_EDGES, 0, 16 * sizeof(int), stream);
  hist_deg<<<(N_EDGES + 255) / 256, 256, 0, stream>>>(dst, deg);
  exscan_kernel<<<1, 1024, 0, stream>>>(deg, offs);
  hipMemcpyAsync(cursor, offs, sizeof(int) * N_NODES, hipMemcpyDeviceToDevice, stream);
  scatter_edges<<<(N_EDGES + 255) / 256, 256, 0, stream>>>(src, dst, cursor, csr_src, csr_eid);

  pack_weights<<<(2 * DEPTH_ * 40 * KPAD * 8 + 255) / 256, 256, 0, stream>>>(W1, W2, Bp1, Bp2);
  pack_wpe<<<(4 * KPAD * 8 + 255) / 256, 256, 0, stream>>>(Wpe, bpe, Bpe);
  proj_nodes<<<((unsigned)NPAD * KPAD + 255) / 256, 256, 0, stream>>>(x, Wpn, bpn, hb);

  for (int i = 0; i < DEPTH_; ++i) {
    node_agg_mfma<<<NPAD, 320, 0, stream>>>(hb, ea, Bpe, csr_src, csr_eid, offs, zb);
    // in-place: zb = relu(zb @ W1 + b1)
    gemm300<1, 1><<<NPAD / 64, 256, 0, stream>>>(zb, Bp1 + (size_t)i * 40 * KPAD * 8, b1 + i * H_, zb);
    if (i < DEPTH_ - 1)
      gemm300<1, 1><<<NPAD / 64, 256, 0, stream>>>(zb, Bp2 + (size_t)i * 40 * KPAD * 8, b2 + i * H_, hb);
    else
      gemm300<0, 0><<<NPAD / 64, 256, 0, stream>>>(zb, Bp2 + (size_t)i * 40 * KPAD * 8, b2 + i * H_, h);
  }

  pool_kernel<<<G_GR, 320, 0, stream>>>(h, bat, pooled);
  final_kernel<<<(G_GR * R_OUT) / 256, 256, 0, stream>>>(pooled, Wsp, bsp, pa, (float*)d_out);
}

// Round 8
// 1955.469 us; speedup vs baseline: 1.4116x; 1.1253x over previous
//
#include <hip/hip_runtime.h>
#include <hip/hip_bf16.h>

#define N_NODES 50000
#define N_EDGES 800000
#define DIN_    64
#define EIN_    16
#define H_      300
#define R_OUT   1024
#define G_GR    256
#define DEPTH_  5
#define KPAD    320
#define NPAD    50048   // multiple of 64 >= N_NODES
#define LDS_S   328     // LDS row stride (bf16 elems) for e-chunk staging

typedef unsigned short ushort_t;
typedef __attribute__((ext_vector_type(8))) short bf16x8;
typedef __attribute__((ext_vector_type(4))) float f32x4;

__device__ __forceinline__ ushort_t f2b(float f) {
  unsigned x = __float_as_uint(f);
  unsigned r = (x + 0x7fffu + ((x >> 16) & 1u)) >> 16;  // RTN-even
  return (ushort_t)r;
}
__device__ __forceinline__ float b2f(ushort_t u) {
  return __uint_as_float((unsigned)u << 16);
}

// ---------------- weight packing (once per call) ----------------
// Pack W1/W2 (fp32 [DEPTH][300][300], k-major) into bf16 frag layout
// Bp[i][kg][n][j] , k = kg*8+j, zero-padded to 320x320.
__global__ void pack_weights(const float* __restrict__ W1, const float* __restrict__ W2,
                             ushort_t* __restrict__ Bp1, ushort_t* __restrict__ Bp2) {
  int idx = blockIdx.x * 256 + threadIdx.x;
  const int per = DEPTH_ * 40 * KPAD * 8;  // 512000
  if (idx >= 2 * per) return;
  const float* W = W1;
  ushort_t* Bp = Bp1;
  int t = idx;
  if (t >= per) { t -= per; W = W2; Bp = Bp2; }
  int j  = t & 7;
  int n  = (t >> 3) % KPAD;
  int kg = ((t >> 3) / KPAD) % 40;
  int i  = t / (40 * KPAD * 8);
  int k  = kg * 8 + j;
  float v = (k < H_ && n < H_) ? W[(i * H_ + k) * H_ + n] : 0.f;
  Bp[t] = f2b(v);
}

// Pack Wpe (fp32 [16][300]) + bpe into frag layout Bpe[kg<4][n<320][j<8],
// K padded to 32 with k==16 row = bpe (bias folded via A k=16 element = 1.0).
__global__ void pack_wpe(const float* __restrict__ Wpe, const float* __restrict__ bpe,
                         ushort_t* __restrict__ Bpe) {
  int t = blockIdx.x * 256 + threadIdx.x;
  if (t >= 4 * KPAD * 8) return;
  int j  = t & 7;
  int n  = (t >> 3) % KPAD;
  int kg = (t >> 3) / KPAD;
  int k  = kg * 8 + j;
  float v = 0.f;
  if (n < H_) {
    if (k < EIN_) v = Wpe[k * H_ + n];
    else if (k == EIN_) v = bpe[n];
  }
  Bpe[t] = f2b(v);
}

// Pack Wpn (fp32 [64][300]) into frag layout Bpn[kg<8][n<320][j<8]
__global__ void pack_wpn(const float* __restrict__ Wpn, ushort_t* __restrict__ Bpn) {
  int t = blockIdx.x * 256 + threadIdx.x;
  if (t >= 8 * KPAD * 8) return;
  int j  = t & 7;
  int n  = (t >> 3) % KPAD;
  int kg = (t >> 3) / KPAD;
  int k  = kg * 8 + j;
  float v = (n < H_) ? Wpn[k * H_ + n] : 0.f;
  Bpn[t] = f2b(v);
}

// ---------------- CSR build (once per call) ----------------
__global__ void hist_deg(const int* __restrict__ dst, int* __restrict__ deg) {
  int e = blockIdx.x * 256 + threadIdx.x;
  if (e < N_EDGES) atomicAdd(deg + dst[e], 1);
}

// single-block exclusive scan of deg[0..N_NODES) -> off, off[N_NODES]=total
__global__ __launch_bounds__(1024) void exscan_kernel(const int* __restrict__ deg,
                                                      int* __restrict__ off) {
  __shared__ int wsum[16];
  __shared__ int carry_s;
  int lane = threadIdx.x & 63;
  int wv = threadIdx.x >> 6;
  if (threadIdx.x == 0) carry_s = 0;
  __syncthreads();
  for (int base = 0; base < N_NODES; base += 1024) {
    int i = base + (int)threadIdx.x;
    int orig = (i < N_NODES) ? deg[i] : 0;
    int v = orig;
#pragma unroll
    for (int s = 1; s < 64; s <<= 1) {
      int u = __shfl_up(v, s);
      if (lane >= s) v += u;
    }
    if (lane == 63) wsum[wv] = v;
    __syncthreads();
    if (wv == 0) {
      int t = (lane < 16) ? wsum[lane] : 0;
#pragma unroll
      for (int s = 1; s < 16; s <<= 1) {
        int u = __shfl_up(t, s);
        if (lane >= s) t += u;
      }
      if (lane < 16) wsum[lane] = t;
    }
    __syncthreads();
    int wbase = (wv > 0) ? wsum[wv - 1] : 0;
    if (i < N_NODES) off[i] = carry_s + wbase + v - orig;
    __syncthreads();
    if (threadIdx.x == 1023) carry_s += wsum[15];
    __syncthreads();
  }
  if (threadIdx.x == 0) off[N_NODES] = carry_s;
}

__global__ void scatter_edges(const int* __restrict__ src, const int* __restrict__ dst,
                              int* __restrict__ cursor, int* __restrict__ csr_src,
                              int* __restrict__ csr_eid) {
  int e = blockIdx.x * 256 + threadIdx.x;
  if (e >= N_EDGES) return;
  int d = dst[e];
  int pos = atomicAdd(cursor + d, 1);
  csr_src[pos] = src[e];
  csr_eid[pos] = e;
}

// ---------------- input projection via MFMA ----------------
// hb[row][col] = bf16(relu(x[row] @ Wpn + bpn)), K=64 (2 k-steps).
// Block 256 = 4 waves; wave: 32 rows x 160 cols. A converted fp32->bf16 on the fly.
__global__ __launch_bounds__(256) void proj_gemm(const float* __restrict__ x,
                                                 const ushort_t* __restrict__ Bpn,
                                                 const float* __restrict__ bpn,
                                                 ushort_t* __restrict__ hb) {
  int lane = threadIdx.x & 63;
  int wid  = threadIdx.x >> 6;
  int lr = lane & 15, lg = lane >> 4;
  int rowblk  = blockIdx.x * 64 + (wid & 1) * 32;
  int colbase = (wid >> 1) * 160;
  int ar0 = rowblk + lr;       if (ar0 >= N_NODES) ar0 = 0;
  int ar1 = rowblk + 16 + lr;  if (ar1 >= N_NODES) ar1 = 0;
  f32x4 acc[2][10];
#pragma unroll
  for (int a = 0; a < 2; ++a)
#pragma unroll
    for (int c = 0; c < 10; ++c) acc[a][c] = (f32x4){0.f, 0.f, 0.f, 0.f};

#pragma unroll
  for (int ks = 0; ks < 2; ++ks) {
    int k0 = ks * 32;
    const float* xr0 = x + (size_t)ar0 * DIN_ + k0 + lg * 8;
    const float* xr1 = x + (size_t)ar1 * DIN_ + k0 + lg * 8;
    f32x4 l0 = *(const f32x4*)xr0, h0 = *(const f32x4*)(xr0 + 4);
    f32x4 l1 = *(const f32x4*)xr1, h1 = *(const f32x4*)(xr1 + 4);
    bf16x8 a0, a1;
#pragma unroll
    for (int j = 0; j < 4; ++j) {
      a0[j] = (short)f2b(l0[j]); a0[j + 4] = (short)f2b(h0[j]);
      a1[j] = (short)f2b(l1[j]); a1[j + 4] = (short)f2b(h1[j]);
    }
    const ushort_t* bb = Bpn + ((unsigned)(k0 / 8 + lg) * KPAD + colbase + lr) * 8;
#pragma unroll
    for (int c = 0; c < 10; ++c) {
      bf16x8 b = *(const bf16x8*)(bb + c * 16 * 8);
      acc[0][c] = __builtin_amdgcn_mfma_f32_16x16x32_bf16(a0, b, acc[0][c], 0, 0, 0);
      acc[1][c] = __builtin_amdgcn_mfma_f32_16x16x32_bf16(a1, b, acc[1][c], 0, 0, 0);
    }
  }
#pragma unroll
  for (int rt = 0; rt < 2; ++rt) {
#pragma unroll
    for (int c = 0; c < 10; ++c) {
      int col = colbase + c * 16 + lr;
      float bv = (col < H_) ? bpn[col] : 0.f;
#pragma unroll
      for (int r = 0; r < 4; ++r) {
        int row = rowblk + rt * 16 + lg * 4 + r;
        if (row >= N_NODES) continue;
        float v = fmaxf(acc[rt][c][r] + bv, 0.f);
        if (col >= H_) v = 0.f;
        hb[(unsigned)row * KPAD + col] = f2b(v);
      }
    }
  }
}

// ---------------- fused edge-MLP + aggregation ----------------
// zb[n][t] = bf16( hb[n][t] + sum_{p in CSR(n)} relu(hb[src_p][t] + (ea[eid_p]@Wpe+bpe)[t]) )
// Block = 1 node, 320 thr = 5 waves. Per 16-edge chunk:
//  phase 1: e-MLP via MFMA (wave w covers cols [64w,64w+64)), result -> LDS [16][320]
//  phase 2: thread t owns col t: per edge one coalesced 640B row-gather of hb[src]
//           + stride-1 LDS read; accumulate relu. No cross-lane reduction.
// csr_src/csr_eid padded with >=16 zero entries past N_EDGES.
__global__ __launch_bounds__(320) void node_agg_mfma(const ushort_t* __restrict__ hb,
                                                     const float* __restrict__ ea,
                                                     const ushort_t* __restrict__ Bpe,
                                                     const int* __restrict__ csr_src,
                                                     const int* __restrict__ csr_eid,
                                                     const int* __restrict__ off,
                                                     ushort_t* zb) {
  __shared__ ushort_t lds_e[16 * LDS_S];
  int n = blockIdx.x;
  int tid = threadIdx.x;
  if (n >= N_NODES) {
    zb[(unsigned)n * KPAD + tid] = 0;
    return;
  }
  int lane = tid & 63;
  int w = tid >> 6;  // wave 0..4
  int lr = lane & 15, lg = lane >> 4;
  int p0 = __builtin_amdgcn_readfirstlane(off[n]);
  int p1 = __builtin_amdgcn_readfirstlane(off[n + 1]);

  // B-frags for this wave's 4 col-tiles (constant across chunks)
  bf16x8 bfr[4];
#pragma unroll
  for (int t = 0; t < 4; ++t) {
    int col = w * 64 + t * 16 + lr;
    bfr[t] = *(const bf16x8*)(Bpe + ((unsigned)lg * KPAD + col) * 8);
  }

  float acc = 0.f;
  for (int pc = p0; pc < p1; pc += 16) {
    int cnt = p1 - pc; if (cnt > 16) cnt = 16;
    // ---- phase 1: e-MLP for up to 16 edges -> LDS
    int eid = csr_eid[pc + lr];
    bf16x8 afr = (bf16x8){0, 0, 0, 0, 0, 0, 0, 0};
    if (lg < 2) {
      const float* ar = ea + (size_t)eid * EIN_ + lg * 8;
      f32x4 lo = *(const f32x4*)ar;
      f32x4 hi = *(const f32x4*)(ar + 4);
#pragma unroll
      for (int j = 0; j < 4; ++j) {
        afr[j] = (short)f2b(lo[j]);
        afr[j + 4] = (short)f2b(hi[j]);
      }
    } else if (lg == 2) {
      afr[0] = (short)0x3F80;  // k==16 -> 1.0 selects bias row of Bpe
    }
#pragma unroll
    for (int t = 0; t < 4; ++t) {
      f32x4 e4 = __builtin_amdgcn_mfma_f32_16x16x32_bf16(afr, bfr[t], (f32x4){0.f, 0.f, 0.f, 0.f}, 0, 0, 0);
      int col = w * 64 + t * 16 + lr;
#pragma unroll
      for (int r = 0; r < 4; ++r)
        lds_e[(lg * 4 + r) * LDS_S + col] = f2b(e4[r]);
    }
    __syncthreads();
    // ---- phase 2: per-col accumulate over edges (coalesced row gathers)
    int e = 0;
    for (; e + 4 <= cnt; e += 4) {
      int s0 = csr_src[pc + e + 0];
      int s1 = csr_src[pc + e + 1];
      int s2 = csr_src[pc + e + 2];
      int s3 = csr_src[pc + e + 3];
      float g0 = b2f(hb[(unsigned)s0 * KPAD + tid]);
      float g1 = b2f(hb[(unsigned)s1 * KPAD + tid]);
      float g2 = b2f(hb[(unsigned)s2 * KPAD + tid]);
      float g3 = b2f(hb[(unsigned)s3 * KPAD + tid]);
      float e0 = b2f(lds_e[(e + 0) * LDS_S + tid]);
      float e1 = b2f(lds_e[(e + 1) * LDS_S + tid]);
      float e2 = b2f(lds_e[(e + 2) * LDS_S + tid]);
      float e3 = b2f(lds_e[(e + 3) * LDS_S + tid]);
      acc += fmaxf(g0 + e0, 0.f);
      acc += fmaxf(g1 + e1, 0.f);
      acc += fmaxf(g2 + e2, 0.f);
      acc += fmaxf(g3 + e3, 0.f);
    }
    for (; e < cnt; ++e) {
      int s = csr_src[pc + e];
      float g = b2f(hb[(unsigned)s * KPAD + tid]);
      float ev = b2f(lds_e[e * LDS_S + tid]);
      acc += fmaxf(g + ev, 0.f);
    }
    __syncthreads();
  }
  unsigned zi = (unsigned)n * KPAD + tid;
  zb[zi] = f2b(b2f(hb[zi]) + acc);
}

// C = act(A @ W + bias).  A: bf16 [NPAD][320].  Bp: frag-packed bf16 [40][320][8].
// OUT_BF16: write bf16 [NPAD][320] (pad cols = 0); else fp32 [N][300].
// Supports in-place A==Cout (block b touches only rows [64b,64b+64);
// __syncthreads() separates all A-reads from C-writes).
template <int RELU_OUT, int OUT_BF16>
__global__ __launch_bounds__(256) void gemm300(const ushort_t* A,
                                               const ushort_t* __restrict__ Bp,
                                               const float* __restrict__ bias,
                                               void* Cout) {
  int lane = threadIdx.x & 63;
  int wid  = threadIdx.x >> 6;
  int lr = lane & 15, lg = lane >> 4;
  int rowblk  = blockIdx.x * 64 + (wid & 1) * 32;  // wave: 32 rows x 160 cols
  int colbase = (wid >> 1) * 160;
  f32x4 acc[2][10];
#pragma unroll
  for (int a = 0; a < 2; ++a)
#pragma unroll
    for (int c = 0; c < 10; ++c) acc[a][c] = (f32x4){0.f, 0.f, 0.f, 0.f};

  const ushort_t* Ap = A + (unsigned)(rowblk + lr) * KPAD + lg * 8;
  for (int k0 = 0; k0 < KPAD; k0 += 32) {
    bf16x8 a0 = *(const bf16x8*)(Ap + k0);
    bf16x8 a1 = *(const bf16x8*)(Ap + 16 * KPAD + k0);
    const ushort_t* bb = Bp + ((unsigned)(k0 / 8 + lg) * KPAD + colbase + lr) * 8;
#pragma unroll
    for (int c = 0; c < 10; ++c) {
      bf16x8 b = *(const bf16x8*)(bb + c * 16 * 8);
      acc[0][c] = __builtin_amdgcn_mfma_f32_16x16x32_bf16(a0, b, acc[0][c], 0, 0, 0);
      acc[1][c] = __builtin_amdgcn_mfma_f32_16x16x32_bf16(a1, b, acc[1][c], 0, 0, 0);
    }
  }
  __syncthreads();  // all A-reads done before any in-place C-write
  // epilogue: D mapping col=lane&15, row=(lane>>4)*4+r  [m89/m91]
#pragma unroll
  for (int rt = 0; rt < 2; ++rt) {
#pragma unroll
    for (int c = 0; c < 10; ++c) {
      int col = colbase + c * 16 + lr;
      float bv = (col < H_) ? bias[col] : 0.f;
#pragma unroll
      for (int r = 0; r < 4; ++r) {
        int row = rowblk + rt * 16 + lg * 4 + r;
        if (row >= N_NODES) continue;
        float v = acc[rt][c][r] + bv;
        if (RELU_OUT) v = fmaxf(v, 0.f);
        if (OUT_BF16) {
          ((ushort_t*)Cout)[(unsigned)row * KPAD + col] = f2b(v);
        } else if (col < H_) {
          ((float*)Cout)[(unsigned)row * H_ + col] = v;
        }
      }
    }
  }
}

// pooled[g] = sum of h rows with batch==g (batch sorted -> binary search bounds)
__global__ void pool_kernel(const float* __restrict__ h, const int* __restrict__ batch,
                            float* __restrict__ pooled) {
  int g = blockIdx.x;
  int hh = threadIdx.x;  // block 320
  int lo = 0, hi = N_NODES;
  while (lo < hi) { int mid = (lo + hi) >> 1; if (batch[mid] < g) lo = mid + 1; else hi = mid; }
  int start = lo;
  hi = N_NODES;
  while (lo < hi) { int mid = (lo + hi) >> 1; if (batch[mid] < g + 1) lo = mid + 1; else hi = mid; }
  int end = lo;
  if (hh >= H_) return;
  float s = 0.f;
  for (int n = start; n < end; ++n) s += h[(unsigned)n * H_ + hh];
  pooled[g * H_ + hh] = s;
}

// out = prelu(pooled @ W_sp + b_sp)
__global__ void final_kernel(const float* __restrict__ pooled, const float* __restrict__ Wsp,
                             const float* __restrict__ bsp, const float* __restrict__ pa,
                             float* __restrict__ out) {
  int f = blockIdx.x * 256 + threadIdx.x;
  if (f >= G_GR * R_OUT) return;
  int g = f >> 10, r = f & 1023;
  float acc = bsp[r];
  const float* pr = pooled + g * H_;
  const float* wc = Wsp + r;
  for (int k = 0; k < H_; ++k) acc += pr[k] * wc[k * R_OUT];
  float a = pa[0];
  out[f] = acc >= 0.f ? acc : a * acc;
}

extern "C" void kernel_launch(void* const* d_in, const int* in_sizes, int n_in,
                              void* d_out, int out_size, void* d_ws, size_t ws_size,
                              hipStream_t stream) {
  const float* x   = (const float*)d_in[0];
  const float* ea  = (const float*)d_in[1];
  const int*   ei  = (const int*)d_in[2];
  const int*   bat = (const int*)d_in[3];
  const float* Wpn = (const float*)d_in[4];
  const float* bpn = (const float*)d_in[5];
  const float* Wpe = (const float*)d_in[6];
  const float* bpe = (const float*)d_in[7];
  const float* W1  = (const float*)d_in[8];
  const float* b1  = (const float*)d_in[9];
  const float* W2  = (const float*)d_in[10];
  const float* b2  = (const float*)d_in[11];
  const float* Wsp = (const float*)d_in[12];
  const float* bsp = (const float*)d_in[13];
  const float* pa  = (const float*)d_in[14];
  const int* src = ei;
  const int* dst = ei + N_EDGES;

  char* ws = (char*)d_ws;
  size_t off_b = 0;
  auto alloc = [&](size_t bytes) {
    void* p = ws + off_b;
    off_b += (bytes + 255) & ~(size_t)255;
    return p;
  };
  ushort_t* hb      = (ushort_t*)alloc(sizeof(ushort_t) * (size_t)NPAD * KPAD);  // 32 MB
  ushort_t* zb      = (ushort_t*)alloc(sizeof(ushort_t) * (size_t)NPAD * KPAD);  // 32 MB
  float*    h       = (float*)alloc(sizeof(float) * (size_t)N_NODES * H_);       // 60 MB
  ushort_t* Bp1     = (ushort_t*)alloc(sizeof(ushort_t) * (size_t)DEPTH_ * 40 * KPAD * 8);
  ushort_t* Bp2     = (ushort_t*)alloc(sizeof(ushort_t) * (size_t)DEPTH_ * 40 * KPAD * 8);
  ushort_t* Bpe     = (ushort_t*)alloc(sizeof(ushort_t) * (size_t)4 * KPAD * 8);
  ushort_t* Bpn     = (ushort_t*)alloc(sizeof(ushort_t) * (size_t)8 * KPAD * 8);
  float*    pooled  = (float*)alloc(sizeof(float) * (size_t)G_GR * H_);
  int*      deg     = (int*)alloc(sizeof(int) * N_NODES);
  int*      offs    = (int*)alloc(sizeof(int) * (N_NODES + 1));
  int*      cursor  = (int*)alloc(sizeof(int) * N_NODES);
  int*      csr_src = (int*)alloc(sizeof(int) * (N_EDGES + 16));  // +16 zero pad
  int*      csr_eid = (int*)alloc(sizeof(int) * (N_EDGES + 16));  // +16 zero pad

  // ---- CSR build ----
  hipMemsetAsync(deg, 0, sizeof(int) * N_NODES, stream);
  hipMemsetAsync(csr_src + N_EDGES, 0, 16 * sizeof(int), stream);
  hipMemsetAsync(csr_eid + N_EDGES, 0, 16 * sizeof(int), stream);
  hist_deg<<<(N_EDGES + 255) / 256, 256, 0, stream>>>(dst, deg);
  exscan_kernel<<<1, 1024, 0, stream>>>(deg, offs);
  hipMemcpyAsync(cursor, offs, sizeof(int) * N_NODES, hipMemcpyDeviceToDevice, stream);
  scatter_edges<<<(N_EDGES + 255) / 256, 256, 0, stream>>>(src, dst, cursor, csr_src, csr_eid);

  pack_weights<<<(2 * DEPTH_ * 40 * KPAD * 8 + 255) / 256, 256, 0, stream>>>(W1, W2, Bp1, Bp2);
  pack_wpe<<<(4 * KPAD * 8 + 255) / 256, 256, 0, stream>>>(Wpe, bpe, Bpe);
  pack_wpn<<<(8 * KPAD * 8 + 255) / 256, 256, 0, stream>>>(Wpn, Bpn);
  proj_gemm<<<NPAD / 64, 256, 0, stream>>>(x, Bpn, bpn, hb);

  for (int i = 0; i < DEPTH_; ++i) {
    node_agg_mfma<<<NPAD, 320, 0, stream>>>(hb, ea, Bpe, csr_src, csr_eid, offs, zb);
    // in-place: zb = relu(zb @ W1 + b1)
    gemm300<1, 1><<<NPAD / 64, 256, 0, stream>>>(zb, Bp1 + (size_t)i * 40 * KPAD * 8, b1 + i * H_, zb);
    if (i < DEPTH_ - 1)
      gemm300<1, 1><<<NPAD / 64, 256, 0, stream>>>(zb, Bp2 + (size_t)i * 40 * KPAD * 8, b2 + i * H_, hb);
    else
      gemm300<0, 0><<<NPAD / 64, 256, 0, stream>>>(zb, Bp2 + (size_t)i * 40 * KPAD * 8, b2 + i * H_, h);
  }

  pool_kernel<<<G_GR, 320, 0, stream>>>(h, bat, pooled);
  final_kernel<<<(G_GR * R_OUT) / 256, 256, 0, stream>>>(pooled, Wsp, bsp, pa, (float*)d_out);
}